// Round 17
// baseline (121.036 us; speedup 1.0000x reference)
//
#include <hip/hip_runtime.h>
#include <hip/hip_bf16.h>

#define B_ 8
#define D_ 128
#define S_ 4096

typedef short short8 __attribute__((ext_vector_type(8)));
typedef float f32x4  __attribute__((ext_vector_type(4)));
typedef float f32x16 __attribute__((ext_vector_type(16)));
typedef unsigned int uint;
typedef uint uint4v __attribute__((ext_vector_type(4)));

#define EXP2F(x) exp2f(x)

__device__ __forceinline__ short f2bf(float f) {
    __hip_bfloat16 h = __float2bfloat16(f);
    return *reinterpret_cast<short*>(&h);
}

// pack two f32 -> one u32 of 2 bf16 (elem0 = lo word)
__device__ __forceinline__ uint cvtpk(float lo, float hi) {
    uint r;
    asm("v_cvt_pk_bf16_f32 %0, %1, %2" : "=v"(r) : "v"(lo), "v"(hi));
    return r;
}

// async global->LDS DMA, 16B/lane; LDS dest = wave-uniform base + lane*16
__device__ __forceinline__ void gload16(const void* g, void* l) {
    __builtin_amdgcn_global_load_lds(
        (const __attribute__((address_space(1))) void*)g,
        (__attribute__((address_space(3))) void*)l, 16, 0, 0);
}

__device__ __forceinline__ float max3f(float a, float b, float c) {
    return fmaxf(fmaxf(a, b), c);    // clang fuses to v_max3_f32
}

// ---------------------------------------------------------------------------
// Kernel 0: pack Wq/Wk/Wv into bf16 MFMA fragments (16x16x32 layout for qkv).
// ---------------------------------------------------------------------------
__global__ __launch_bounds__(256) void wpack_kernel(
    const float* __restrict__ Wq, const float* __restrict__ Wk,
    const float* __restrict__ Wv, short* __restrict__ Wf)
{
    int g = blockIdx.x * 256 + threadIdx.x;      // 0..6143
    int lane = g & 63, kc = (g >> 6) & 3, n = (g >> 8) & 7, wm = g >> 11;
    const float* W = (wm == 0) ? Wq : (wm == 1) ? Wk : Wv;
    int row = n * 16 + (lane & 15);
    int col = kc * 32 + (lane >> 4) * 8;
    short8 o;
    #pragma unroll
    for (int j = 0; j < 8; ++j) o[j] = f2bf(W[row * 128 + col + j]);
    *((short8*)Wf + g) = o;
}

// ---------------------------------------------------------------------------
// Kernel 1: QKV projection via bf16 MFMA (16x16x32), unchanged.
// Q: (B,S,D) bf16 scaled by log2(e)/sqrt(D). K: (B,S,D). V: (B,D,S).
// ---------------------------------------------------------------------------
__global__ __launch_bounds__(256) void qkv_kernel(
    const float* __restrict__ x, const short* __restrict__ Wf,
    const float* __restrict__ bq, const float* __restrict__ bk,
    const float* __restrict__ bv,
    short* __restrict__ Qo, short* __restrict__ Ko, short* __restrict__ Vo)
{
    __shared__ float xt[64 * 132];
    const int b  = blockIdx.y;
    const int s0 = blockIdx.x * 64;
    const int t  = threadIdx.x;
    const int w    = t >> 6;
    const int lane = t & 63;
    const int lr   = lane & 15;
    const int lg   = lane >> 4;

    const float* xb = x + (size_t)b * D_ * S_;
    #pragma unroll
    for (int it = 0; it < 32; ++it) {
        int d = it * 4 + (t >> 6);
        int s = t & 63;
        xt[s * 132 + d] = xb[(size_t)d * S_ + s0 + s];
    }
    __syncthreads();

    short8 xtf[4];
    {
        const float* base = &xt[(w * 16 + lr) * 132 + lg * 8];
        #pragma unroll
        for (int kc = 0; kc < 4; ++kc) {
            float4 a = *(const float4*)(base + kc * 32);
            float4 c = *(const float4*)(base + kc * 32 + 4);
            short8 f;
            f[0] = f2bf(a.x); f[1] = f2bf(a.y); f[2] = f2bf(a.z); f[3] = f2bf(a.w);
            f[4] = f2bf(c.x); f[5] = f2bf(c.y); f[6] = f2bf(c.z); f[7] = f2bf(c.w);
            xtf[kc] = f;
        }
    }

    const float qs = 0.08838834764831845f * 1.4426950408889634f;
    const short8* W8 = (const short8*)Wf;
    const size_t bSD = (size_t)b * S_ * D_;
    const size_t bDS = (size_t)b * D_ * S_;

    #pragma unroll
    for (int n = 0; n < 8; ++n) {
        f32x4 aq = (f32x4){0.f, 0.f, 0.f, 0.f};
        f32x4 ak = (f32x4){0.f, 0.f, 0.f, 0.f};
        f32x4 av = (f32x4){0.f, 0.f, 0.f, 0.f};
        #pragma unroll
        for (int kc = 0; kc < 4; ++kc) {
            short8 wq = W8[(      n * 4 + kc) * 64 + lane];
            short8 wk = W8[(32  + n * 4 + kc) * 64 + lane];
            short8 wv = W8[(64  + n * 4 + kc) * 64 + lane];
            aq = __builtin_amdgcn_mfma_f32_16x16x32_bf16(xtf[kc], wq, aq, 0, 0, 0);
            ak = __builtin_amdgcn_mfma_f32_16x16x32_bf16(xtf[kc], wk, ak, 0, 0, 0);
            av = __builtin_amdgcn_mfma_f32_16x16x32_bf16(wv, xtf[kc], av, 0, 0, 0);
        }
        int e = n * 16 + lr;
        float bqe = bq[e], bke = bk[e];
        #pragma unroll
        for (int r = 0; r < 4; ++r) {
            size_t off = (bSD + (size_t)(s0 + w * 16 + lg * 4 + r) * D_) + e;
            Qo[off] = f2bf((aq[r] + bqe) * qs);
            Ko[off] = f2bf(ak[r] + bke);
        }
        #pragma unroll
        for (int r = 0; r < 4; ++r) {
            int ev = n * 16 + lg * 4 + r;
            Vo[bDS + (size_t)ev * S_ + s0 + w * 16 + lr] = f2bf(av[r] + bv[ev]);
        }
    }
}

// ---------------------------------------------------------------------------
// Kernel 2: flash attention (R9 base) restructured as SEQUENTIAL HALF-SUBTILE
// online softmax: each 64-kv staged tile is processed as two exact 32-kv
// online-softmax sub-steps:
//   QK0 -> [QK1 || maxtree0]SGB -> gate0 -> exp0/pack0
//       -> [PV0 || maxtree1+sums0]SGB -> gate1 -> exp1/pack1 -> PV1(+sums1)
// This creates two regions where an 8-MFMA chain and independent VALU are
// co-live in ONE basic block with NO acc carried across barriers (register
// state <= R9 -- R12's spill cause absent). T19 sched_group_barrier quotas
// pin the interleave. Numerically exact (standard flash sub-tiling; gate1's
// rescale covers PV0's o-contribution and sums0, both completed before it).
// All staging/prefetch/layout identical to the verified R9.
// C/D layout (m74/m101): col=lane&31, row=(reg&3)+8*(reg>>2)+4*(lane>>5).
// ---------------------------------------------------------------------------
__global__ __launch_bounds__(512, 2) void attn_kernel(
    const short* __restrict__ Q, const short* __restrict__ K,
    const short* __restrict__ Vt, const float* __restrict__ x,
    float* __restrict__ out)
{
    extern __shared__ __align__(16) char smem[];   // 131072 B
    const int lin = blockIdx.x;
    const int b   = lin & 7;            // XCD swizzle: one b per XCD
    const int q0  = (lin >> 3) * 128;
    const int tid  = threadIdx.x;
    const int w    = tid >> 6;
    const int lane = tid & 63;
    const int q    = lane & 31;         // this lane's q column
    const int hi   = lane >> 5;
    const int half = w >> 2;            // KV half: kt 0..31 -> rows half*2048..
    const int ww   = w & 3;             // q strip (q0 + ww*32 ..)

    const size_t bSD = (size_t)b * S_ * D_;

    // Q fragments: qf[c][j] = Q[q0+ww*32+q][c*16 + hi*8 + j]
    short8 qf[8];
    {
        const short* Qrow = Q + bSD + (size_t)(q0 + ww * 32 + q) * D_ + hi * 8;
        #pragma unroll
        for (int c = 0; c < 8; ++c)
            qf[c] = *(const short8*)(Qrow + c * 16);
    }

    f32x16 o[4];
    #pragma unroll
    for (int dt = 0; dt < 4; ++dt)
        #pragma unroll
        for (int i = 0; i < 16; ++i) o[dt][i] = 0.f;
    float m = -1e30f, lsum = 0.f;      // lsum LANE-PARTIAL until after loop

    const short* Kb = K + bSD;
    const short* Vb = Vt + (size_t)b * D_ * S_;
    const int ktbase = half * 32;

    // DMA-stage one 64-kv tile of this wave's half into buffer `buf`.
    // LDS dest linear; global src pre-swizzled (phys 16B-chunk c of row r
    // holds logical chunk c^(r&7)).
    auto stage = [&](int kt, int buf) {
        const short* Kg = Kb + (size_t)(ktbase + kt) * 64 * D_;
        const short* Vg = Vb + (size_t)(ktbase + kt) * 64;
        char* Kd = smem + buf * 65536 + half * 32768;
        char* Vd = Kd + 16384;
        #pragma unroll
        for (int i = 0; i < 4; ++i) {
            int ki = ww * 4 + i;                 // 1KB chunk: rows 4ki..4ki+3
            int r  = ki * 4 + (lane >> 4);
            gload16(Kg + r * D_ + (((lane & 15) ^ (r & 7)) * 8), Kd + ki * 1024);
        }
        #pragma unroll
        for (int i = 0; i < 4; ++i) {
            int vi = ww * 4 + i;                 // 1KB chunk: rows 8vi..8vi+7
            int r  = vi * 8 + (lane >> 3);
            gload16(Vg + (size_t)r * S_ + (((lane & 7) ^ (lane >> 3)) * 8),
                    Vd + vi * 1024);
        }
    };

    // half-subtile softmax epilogue pieces -----------------------------------
    // gate: cross-half'd tile max tm -> T13 defer-max rescale of o/m/lsum.
    auto gate = [&](float tm) {
        if (!__all(tm <= m + 8.f)) {
            float mn   = fmaxf(m, tm);
            float corr = EXP2F(m - mn);
            m = mn; lsum *= corr;
            #pragma unroll
            for (int dt = 0; dt < 4; ++dt)
                #pragma unroll
                for (int r = 0; r < 16; ++r) o[dt][r] *= corr;
        }
    };
    // exp + pack one 16-elem acc half into pf[2] (distinct SSA defs: safe).
    auto exppack = [&](f32x16& A, short8* pf) {
        #pragma unroll
        for (int r = 0; r < 16; ++r) A[r] = EXP2F(A[r] - m);
        #pragma unroll
        for (int kc = 0; kc < 2; ++kc) {
            int c1 = kc * 8;
            uint W0 = cvtpk(A[c1 + 0], A[c1 + 1]);
            uint W1 = cvtpk(A[c1 + 2], A[c1 + 3]);
            uint W2 = cvtpk(A[c1 + 4], A[c1 + 5]);
            uint W3 = cvtpk(A[c1 + 6], A[c1 + 7]);
            asm("v_permlane32_swap_b32 %0, %1" : "+v"(W0), "+v"(W2));
            asm("v_permlane32_swap_b32 %0, %1" : "+v"(W1), "+v"(W3));
            uint4v pw;
            pw.x = W0; pw.y = W1; pw.z = W2; pw.w = W3;
            pf[kc] = *reinterpret_cast<short8*>(&pw);
        }
    };
    // 16-elem v_max3 tree.
    auto tree16 = [&](const f32x16& A) -> float {
        float x0 = max3f(A[0],  A[1],  A[2]);
        float x1 = max3f(A[3],  A[4],  A[5]);
        float x2 = max3f(A[6],  A[7],  A[8]);
        float x3 = max3f(A[9],  A[10], A[11]);
        float x4 = max3f(A[12], A[13], A[14]);
        float y0 = max3f(x0, x1, x2);
        float y1 = max3f(x3, x4, A[15]);
        return fmaxf(y0, y1);
    };
    auto sum16 = [&](const f32x16& A) -> float {
        float s0 = ((A[0]+A[1])+(A[2]+A[3])) + ((A[4]+A[5])+(A[6]+A[7]));
        float s1 = ((A[8]+A[9])+(A[10]+A[11])) + ((A[12]+A[13])+(A[14]+A[15]));
        return s0 + s1;
    };

    stage(0, 0);
    __syncthreads();                 // drains vmcnt -> buf0 ready
    int cur = 0;

    for (int kt = 0; kt < 32; ++kt) {
        if (kt + 1 < 32) stage(kt + 1, cur ^ 1);   // DMA overlaps compute

        const char* Kh = smem + cur * 65536 + half * 32768;
        const char* Vh = Kh + 16384;

        // ================= sub-step 0: QK0 (k rows 0..31) ==================
        f32x16 acc0, acc1;
        #pragma unroll
        for (int i = 0; i < 16; ++i) acc0[i] = 0.f;
        short8 kf[3];
        {
            int co0 = ((0 + hi) ^ (q & 7)) * 16;
            int co1 = ((2 + hi) ^ (q & 7)) * 16;
            kf[0] = *(const short8*)(Kh + q * 256 + co0);
            kf[1] = *(const short8*)(Kh + q * 256 + co1);
        }
        #pragma unroll
        for (int c = 0; c < 8; ++c) {
            if (c < 6) {
                int co = (((c + 2) * 2 + hi) ^ (q & 7)) * 16;
                kf[(c + 2) % 3] = *(const short8*)(Kh + q * 256 + co);
            }
            acc0 = __builtin_amdgcn_mfma_f32_32x32x16_bf16(kf[c % 3], qf[c], acc0, 0, 0, 0);
        }

        // ====== region A: QK1 (k rows 32..63) || maxtree0, SGB-pinned ======
        #pragma unroll
        for (int i = 0; i < 16; ++i) acc1[i] = 0.f;
        short8 kg[3];
        {
            int co0 = ((0 + hi) ^ (q & 7)) * 16;
            int co1 = ((2 + hi) ^ (q & 7)) * 16;
            kg[0] = *(const short8*)(Kh + (32 + q) * 256 + co0);
            kg[1] = *(const short8*)(Kh + (32 + q) * 256 + co1);
        }
        #pragma unroll
        for (int c = 0; c < 8; ++c) {
            if (c < 6) {
                int co = (((c + 2) * 2 + hi) ^ (q & 7)) * 16;
                kg[(c + 2) % 3] = *(const short8*)(Kh + (32 + q) * 256 + co);
            }
            acc1 = __builtin_amdgcn_mfma_f32_32x32x16_bf16(kg[c % 3], qf[c], acc1, 0, 0, 0);
        }
        float tm0 = tree16(acc0);
        // SGB template: interleave {1 DS_READ, 1 MFMA, 2 VALU} per chain step.
        #pragma unroll
        for (int g = 0; g < 6; ++g) {
            __builtin_amdgcn_sched_group_barrier(0x100, 1, 0);  // DS_READ
            __builtin_amdgcn_sched_group_barrier(0x008, 1, 0);  // MFMA
            __builtin_amdgcn_sched_group_barrier(0x002, 2, 0);  // VALU
        }
        __builtin_amdgcn_sched_group_barrier(0x008, 1, 0);
        __builtin_amdgcn_sched_group_barrier(0x002, 2, 0);
        __builtin_amdgcn_sched_group_barrier(0x008, 1, 0);

        tm0 = fmaxf(tm0, __shfl_xor(tm0, 32));
        gate(tm0);
        short8 pf0[2];
        exppack(acc0, pf0);

        // ===== region B: PV0 (kc 0,1) || maxtree1 + sums0, SGB-pinned ======
        short8 vf[3];
        {
            int co0 = ((0 + hi) ^ (q & 7)) * 16;     // kc=0
            vf[0] = *(const short8*)(Vh + (0 * 32 + q) * 128 + co0);
            vf[1] = *(const short8*)(Vh + (1 * 32 + q) * 128 + co0);
        }
        #pragma unroll
        for (int i = 0; i < 8; ++i) {
            if (i < 6) {
                int j  = i + 2;
                int co = (((j >> 2) * 2 + hi) ^ (q & 7)) * 16;
                vf[j % 3] = *(const short8*)(Vh + ((j & 3) * 32 + q) * 128 + co);
            }
            o[i & 3] = __builtin_amdgcn_mfma_f32_32x32x16_bf16(
                vf[i % 3], pf0[i >> 2], o[i & 3], 0, 0, 0);
        }
        float tm1 = tree16(acc1);
        lsum += sum16(acc0);
        #pragma unroll
        for (int g = 0; g < 6; ++g) {
            __builtin_amdgcn_sched_group_barrier(0x100, 1, 0);  // DS_READ
            __builtin_amdgcn_sched_group_barrier(0x008, 1, 0);  // MFMA
            __builtin_amdgcn_sched_group_barrier(0x002, 4, 0);  // VALU
        }
        __builtin_amdgcn_sched_group_barrier(0x008, 1, 0);
        __builtin_amdgcn_sched_group_barrier(0x002, 2, 0);
        __builtin_amdgcn_sched_group_barrier(0x008, 1, 0);

        tm1 = fmaxf(tm1, __shfl_xor(tm1, 32));
        gate(tm1);
        short8 pf1[2];
        exppack(acc1, pf1);

        // ============ sub-step 1 PV: kc 2,3, sums1 under PV ===============
        {
            int co2 = ((4 + hi) ^ (q & 7)) * 16;     // kc=2
            vf[0] = *(const short8*)(Vh + (0 * 32 + q) * 128 + co2);
            vf[1] = *(const short8*)(Vh + (1 * 32 + q) * 128 + co2);
        }
        lsum += sum16(acc1);
        __builtin_amdgcn_s_setprio(1);
        #pragma unroll
        for (int i = 0; i < 8; ++i) {
            if (i < 6) {
                int j  = i + 2;
                int co = ((((j >> 2) + 2) * 2 + hi) ^ (q & 7)) * 16;
                vf[j % 3] = *(const short8*)(Vh + ((j & 3) * 32 + q) * 128 + co);
            }
            o[i & 3] = __builtin_amdgcn_mfma_f32_32x32x16_bf16(
                vf[i % 3], pf1[i >> 2], o[i & 3], 0, 0, 0);
        }
        __builtin_amdgcn_s_setprio(0);

        __syncthreads();     // reads of buf[cur] done + DMA into buf[cur^1] drained
        cur ^= 1;
    }

    // Complete the cross-half lsum reduction once (exact: halves share m).
    lsum += __shfl_xor(lsum, 32);

    // ---- merge halves through LDS, residual-fused transposed writeout ----
    if (half == 1) {
        float* obuf = (float*)(smem + ww * 16384);
        #pragma unroll
        for (int dt = 0; dt < 4; ++dt)
            #pragma unroll
            for (int r = 0; r < 16; ++r) {
                int dl = dt * 32 + (r & 3) + 8 * (r >> 2) + 4 * hi;
                obuf[dl * 32 + q] = o[dt][r];
            }
        if (hi == 0) {
            float* ml = (float*)(smem + 65536 + ww * 256);
            ml[q * 2]     = m;
            ml[q * 2 + 1] = lsum;
        }
    }
    __syncthreads();
    if (half == 0) {
        const float* obuf = (const float*)(smem + ww * 16384);
        const float* ml   = (const float*)(smem + 65536 + ww * 256);
        float m2 = ml[q * 2], l2 = ml[q * 2 + 1];
        float M  = fmaxf(m, m2);
        float c1 = EXP2F(m - M), c2 = EXP2F(m2 - M);
        float inv = 1.0f / (lsum * c1 + l2 * c2);
        const float* xb = x   + (size_t)b * D_ * S_;
        float*       ob = out + (size_t)b * D_ * S_;
        int s = q0 + ww * 32 + q;
        #pragma unroll
        for (int dt = 0; dt < 4; ++dt)
            #pragma unroll
            for (int r = 0; r < 16; ++r) {
                int dl = dt * 32 + (r & 3) + 8 * (r >> 2) + 4 * hi;
                float val = (o[dt][r] * c1 + obuf[dl * 32 + q] * c2) * inv;
                size_t g = (size_t)dl * S_ + s;
                ob[g] = xb[g] + val;
            }
    }
}

extern "C" void kernel_launch(void* const* d_in, const int* in_sizes, int n_in,
                              void* d_out, int out_size, void* d_ws, size_t ws_size,
                              hipStream_t stream) {
    const float* x  = (const float*)d_in[0];
    const float* Wq = (const float*)d_in[1];
    const float* bq = (const float*)d_in[2];
    const float* Wk = (const float*)d_in[3];
    const float* bk = (const float*)d_in[4];
    const float* Wv = (const float*)d_in[5];
    const float* bv = (const float*)d_in[6];
    float* out = (float*)d_out;

    size_t n = (size_t)B_ * S_ * D_;
    short* Qw = (short*)d_ws;
    short* Kw = Qw + n;
    short* Vw = Kw + n;
    short* Wf = (short*)d_out;   // scratch at head of d_out; fully overwritten

    wpack_kernel<<<24, 256, 0, stream>>>(Wq, Wk, Wv, Wf);

    dim3 grid(S_ / 64, B_);
    qkv_kernel<<<grid, 256, 0, stream>>>(x, Wf, bq, bk, bv, Qw, Kw, Vw);

    int smemB = 131072;
    (void)hipFuncSetAttribute((const void*)attn_kernel,
                              hipFuncAttributeMaxDynamicSharedMemorySize, smemB);
    attn_kernel<<<256, 512, smemB, stream>>>(Qw, Kw, Vw, x, out);
}

// Round 18
// 118.265 us; speedup vs baseline: 1.0234x; 1.0234x over previous
//
#include <hip/hip_runtime.h>
#include <hip/hip_bf16.h>

#define B_ 8
#define D_ 128
#define S_ 4096

typedef short short8 __attribute__((ext_vector_type(8)));
typedef float f32x4  __attribute__((ext_vector_type(4)));
typedef float f32x16 __attribute__((ext_vector_type(16)));
typedef unsigned int uint;
typedef uint uint4v __attribute__((ext_vector_type(4)));

#define EXP2F(x) exp2f(x)

__device__ __forceinline__ short f2bf(float f) {
    __hip_bfloat16 h = __float2bfloat16(f);
    return *reinterpret_cast<short*>(&h);
}

// pack two f32 -> one u32 of 2 bf16 (elem0 = lo word)
__device__ __forceinline__ uint cvtpk(float lo, float hi) {
    uint r;
    asm("v_cvt_pk_bf16_f32 %0, %1, %2" : "=v"(r) : "v"(lo), "v"(hi));
    return r;
}

// async global->LDS DMA, 16B/lane; LDS dest = wave-uniform base + lane*16
__device__ __forceinline__ void gload16(const void* g, void* l) {
    __builtin_amdgcn_global_load_lds(
        (const __attribute__((address_space(1))) void*)g,
        (__attribute__((address_space(3))) void*)l, 16, 0, 0);
}

__device__ __forceinline__ float max3f(float a, float b, float c) {
    return fmaxf(fmaxf(a, b), c);    // clang fuses to v_max3_f32
}

// ---------------------------------------------------------------------------
// Kernel 0: pack Wq/Wk/Wv into bf16 MFMA fragments (16x16x32 layout for qkv).
// ---------------------------------------------------------------------------
__global__ __launch_bounds__(256) void wpack_kernel(
    const float* __restrict__ Wq, const float* __restrict__ Wk,
    const float* __restrict__ Wv, short* __restrict__ Wf)
{
    int g = blockIdx.x * 256 + threadIdx.x;      // 0..6143
    int lane = g & 63, kc = (g >> 6) & 3, n = (g >> 8) & 7, wm = g >> 11;
    const float* W = (wm == 0) ? Wq : (wm == 1) ? Wk : Wv;
    int row = n * 16 + (lane & 15);
    int col = kc * 32 + (lane >> 4) * 8;
    short8 o;
    #pragma unroll
    for (int j = 0; j < 8; ++j) o[j] = f2bf(W[row * 128 + col + j]);
    *((short8*)Wf + g) = o;
}

// ---------------------------------------------------------------------------
// Kernel 1: QKV projection via bf16 MFMA (16x16x32), unchanged.
// Q: (B,S,D) bf16 scaled by log2(e)/sqrt(D). K: (B,S,D). V: (B,D,S).
// ---------------------------------------------------------------------------
__global__ __launch_bounds__(256) void qkv_kernel(
    const float* __restrict__ x, const short* __restrict__ Wf,
    const float* __restrict__ bq, const float* __restrict__ bk,
    const float* __restrict__ bv,
    short* __restrict__ Qo, short* __restrict__ Ko, short* __restrict__ Vo)
{
    __shared__ float xt[64 * 132];
    const int b  = blockIdx.y;
    const int s0 = blockIdx.x * 64;
    const int t  = threadIdx.x;
    const int w    = t >> 6;
    const int lane = t & 63;
    const int lr   = lane & 15;
    const int lg   = lane >> 4;

    const float* xb = x + (size_t)b * D_ * S_;
    #pragma unroll
    for (int it = 0; it < 32; ++it) {
        int d = it * 4 + (t >> 6);
        int s = t & 63;
        xt[s * 132 + d] = xb[(size_t)d * S_ + s0 + s];
    }
    __syncthreads();

    short8 xtf[4];
    {
        const float* base = &xt[(w * 16 + lr) * 132 + lg * 8];
        #pragma unroll
        for (int kc = 0; kc < 4; ++kc) {
            float4 a = *(const float4*)(base + kc * 32);
            float4 c = *(const float4*)(base + kc * 32 + 4);
            short8 f;
            f[0] = f2bf(a.x); f[1] = f2bf(a.y); f[2] = f2bf(a.z); f[3] = f2bf(a.w);
            f[4] = f2bf(c.x); f[5] = f2bf(c.y); f[6] = f2bf(c.z); f[7] = f2bf(c.w);
            xtf[kc] = f;
        }
    }

    const float qs = 0.08838834764831845f * 1.4426950408889634f;
    const short8* W8 = (const short8*)Wf;
    const size_t bSD = (size_t)b * S_ * D_;
    const size_t bDS = (size_t)b * D_ * S_;

    #pragma unroll
    for (int n = 0; n < 8; ++n) {
        f32x4 aq = (f32x4){0.f, 0.f, 0.f, 0.f};
        f32x4 ak = (f32x4){0.f, 0.f, 0.f, 0.f};
        f32x4 av = (f32x4){0.f, 0.f, 0.f, 0.f};
        #pragma unroll
        for (int kc = 0; kc < 4; ++kc) {
            short8 wq = W8[(      n * 4 + kc) * 64 + lane];
            short8 wk = W8[(32  + n * 4 + kc) * 64 + lane];
            short8 wv = W8[(64  + n * 4 + kc) * 64 + lane];
            aq = __builtin_amdgcn_mfma_f32_16x16x32_bf16(xtf[kc], wq, aq, 0, 0, 0);
            ak = __builtin_amdgcn_mfma_f32_16x16x32_bf16(xtf[kc], wk, ak, 0, 0, 0);
            av = __builtin_amdgcn_mfma_f32_16x16x32_bf16(wv, xtf[kc], av, 0, 0, 0);
        }
        int e = n * 16 + lr;
        float bqe = bq[e], bke = bk[e];
        #pragma unroll
        for (int r = 0; r < 4; ++r) {
            size_t off = (bSD + (size_t)(s0 + w * 16 + lg * 4 + r) * D_) + e;
            Qo[off] = f2bf((aq[r] + bqe) * qs);
            Ko[off] = f2bf(ak[r] + bke);
        }
        #pragma unroll
        for (int r = 0; r < 4; ++r) {
            int ev = n * 16 + lg * 4 + r;
            Vo[bDS + (size_t)ev * S_ + s0 + w * 16 + lr] = f2bf(av[r] + bv[ev]);
        }
    }
}

// ---------------------------------------------------------------------------
// Kernel 2: flash attention (R9 -- FINAL: measured best across 17 rounds,
// 113.7-118.3 us total, ~112 us best dispatch, reproduced three times).
// 512 thr = 2 KV-halves x 4 q-strips, 64-kv tiles, K+V DMA-staged,
// double-buffered, 1 barrier/tile; depth-2-pair rotating LDS-read prefetch
// in QK and PV; lane-partial lsum (single cross-half shfl after the loop);
// sum-tree placed after P-pack + V-prefetch (hides under PV); v_max3 tree.
// 17-round exploration record (all worse or null): more waves (R2: spills),
// barrier-free+direct V (R3: uncoalesced), source interleave (R4/R5:
// scheduler clusters phases), cross-block drift (R6), QBLK=64 +- prefetch
// (R7/R15: 1 wave/SIMD exposes serial chain), role dephasing (R10), XOR
// addressing (R11: breaks ds addressing), acc-carry + SGB (R12: spills),
// half-subtile + SGB (R17: overlap not delivered, overhead costs 4%).
// The ~190-reg flash state at D=128 caps occupancy at 2 waves/SIMD; the
// per-tile QK->softmax->PV critical path is the structural plateau at HIP
// source level on this compiler.
// C/D layout (m74/m101): col=lane&31, row=(reg&3)+8*(reg>>2)+4*(lane>>5).
// ---------------------------------------------------------------------------
__global__ __launch_bounds__(512, 2) void attn_kernel(
    const short* __restrict__ Q, const short* __restrict__ K,
    const short* __restrict__ Vt, const float* __restrict__ x,
    float* __restrict__ out)
{
    extern __shared__ __align__(16) char smem[];   // 131072 B
    const int lin = blockIdx.x;
    const int b   = lin & 7;            // XCD swizzle: one b per XCD
    const int q0  = (lin >> 3) * 128;
    const int tid  = threadIdx.x;
    const int w    = tid >> 6;
    const int lane = tid & 63;
    const int q    = lane & 31;         // this lane's q column
    const int hi   = lane >> 5;
    const int half = w >> 2;            // KV half: kt 0..31 -> rows half*2048..
    const int ww   = w & 3;             // q strip (q0 + ww*32 ..)

    const size_t bSD = (size_t)b * S_ * D_;

    // Q fragments: qf[c][j] = Q[q0+ww*32+q][c*16 + hi*8 + j]
    short8 qf[8];
    {
        const short* Qrow = Q + bSD + (size_t)(q0 + ww * 32 + q) * D_ + hi * 8;
        #pragma unroll
        for (int c = 0; c < 8; ++c)
            qf[c] = *(const short8*)(Qrow + c * 16);
    }

    f32x16 o[4];
    #pragma unroll
    for (int dt = 0; dt < 4; ++dt)
        #pragma unroll
        for (int i = 0; i < 16; ++i) o[dt][i] = 0.f;
    float m = -1e30f, lsum = 0.f;      // lsum LANE-PARTIAL until after loop

    const short* Kb = K + bSD;
    const short* Vb = Vt + (size_t)b * D_ * S_;
    const int ktbase = half * 32;

    // DMA-stage one 64-kv tile of this wave's half into buffer `buf`.
    // LDS dest linear; global src pre-swizzled (phys 16B-chunk c of row r
    // holds logical chunk c^(r&7)).
    auto stage = [&](int kt, int buf) {
        const short* Kg = Kb + (size_t)(ktbase + kt) * 64 * D_;
        const short* Vg = Vb + (size_t)(ktbase + kt) * 64;
        char* Kd = smem + buf * 65536 + half * 32768;
        char* Vd = Kd + 16384;
        #pragma unroll
        for (int i = 0; i < 4; ++i) {
            int ki = ww * 4 + i;                 // 1KB chunk: rows 4ki..4ki+3
            int r  = ki * 4 + (lane >> 4);
            gload16(Kg + r * D_ + (((lane & 15) ^ (r & 7)) * 8), Kd + ki * 1024);
        }
        #pragma unroll
        for (int i = 0; i < 4; ++i) {
            int vi = ww * 4 + i;                 // 1KB chunk: rows 8vi..8vi+7
            int r  = vi * 8 + (lane >> 3);
            gload16(Vg + (size_t)r * S_ + (((lane & 7) ^ (lane >> 3)) * 8),
                    Vd + vi * 1024);
        }
    };

    stage(0, 0);
    __syncthreads();                 // drains vmcnt -> buf0 ready
    int cur = 0;

    for (int kt = 0; kt < 32; ++kt) {
        if (kt + 1 < 32) stage(kt + 1, cur ^ 1);   // DMA overlaps compute

        const char* Kh = smem + cur * 65536 + half * 32768;
        const char* Vh = Kh + 16384;

        // ---- S^T = K Q^T : acc[n][r] = S[k = n*32+(r&3)+8*(r>>2)+4*hi][q] --
        // Depth-2-pair rotating prefetch (reads for c+2 issued at step c).
        f32x16 acc0, acc1;
        #pragma unroll
        for (int i = 0; i < 16; ++i) { acc0[i] = 0.f; acc1[i] = 0.f; }
        short8 kf[3][2];
        {
            int co0 = ((0 + hi) ^ (q & 7)) * 16;
            int co1 = ((2 + hi) ^ (q & 7)) * 16;
            kf[0][0] = *(const short8*)(Kh + q * 256 + co0);
            kf[0][1] = *(const short8*)(Kh + (32 + q) * 256 + co0);
            kf[1][0] = *(const short8*)(Kh + q * 256 + co1);
            kf[1][1] = *(const short8*)(Kh + (32 + q) * 256 + co1);
        }
        __builtin_amdgcn_s_setprio(1);
        #pragma unroll
        for (int c = 0; c < 8; ++c) {
            if (c < 6) {
                int co = (((c + 2) * 2 + hi) ^ (q & 7)) * 16;
                kf[(c + 2) % 3][0] = *(const short8*)(Kh + q * 256 + co);
                kf[(c + 2) % 3][1] = *(const short8*)(Kh + (32 + q) * 256 + co);
            }
            acc0 = __builtin_amdgcn_mfma_f32_32x32x16_bf16(kf[c % 3][0], qf[c], acc0, 0, 0, 0);
            acc1 = __builtin_amdgcn_mfma_f32_32x32x16_bf16(kf[c % 3][1], qf[c], acc1, 0, 0, 0);
        }
        __builtin_amdgcn_s_setprio(0);

        // ---- tile max: 3-ary tree (v_max3), then cross-half, T13 gate ----
        float a0 = max3f(acc0[0],  acc0[1],  acc0[2]);
        float a1 = max3f(acc0[3],  acc0[4],  acc0[5]);
        float a2 = max3f(acc0[6],  acc0[7],  acc0[8]);
        float a3 = max3f(acc0[9],  acc0[10], acc0[11]);
        float a4 = max3f(acc0[12], acc0[13], acc0[14]);
        float a5 = max3f(acc1[0],  acc1[1],  acc1[2]);
        float a6 = max3f(acc1[3],  acc1[4],  acc1[5]);
        float a7 = max3f(acc1[6],  acc1[7],  acc1[8]);
        float a8 = max3f(acc1[9],  acc1[10], acc1[11]);
        float a9 = max3f(acc1[12], acc1[13], acc1[14]);
        float b0 = max3f(a0, a1, a2);
        float b1 = max3f(a3, a4, acc0[15]);
        float b2 = max3f(a5, a6, a7);
        float b3 = max3f(a8, a9, acc1[15]);
        float tm = fmaxf(max3f(b0, b1, b2), b3);
        tm = fmaxf(tm, __shfl_xor(tm, 32));
        if (!__all(tm <= m + 8.f)) {
            float mn   = fmaxf(m, tm);
            float corr = EXP2F(m - mn);
            m = mn; lsum *= corr;
            #pragma unroll
            for (int dt = 0; dt < 4; ++dt)
                #pragma unroll
                for (int r = 0; r < 16; ++r) o[dt][r] *= corr;
        }
        #pragma unroll
        for (int r = 0; r < 16; ++r) acc0[r] = EXP2F(acc0[r] - m);
        #pragma unroll
        for (int r = 0; r < 16; ++r) acc1[r] = EXP2F(acc1[r] - m);

        // ---- P -> bf16 PV B-fragments (distinct SSA defs -> permlane safe) --
        short8 pf[4];
        #pragma unroll
        for (int kc = 0; kc < 4; ++kc) {
            const f32x16& a = (kc < 2) ? acc0 : acc1;
            int c1 = (kc & 1) * 8;
            uint W0 = cvtpk(a[c1 + 0], a[c1 + 1]);
            uint W1 = cvtpk(a[c1 + 2], a[c1 + 3]);
            uint W2 = cvtpk(a[c1 + 4], a[c1 + 5]);
            uint W3 = cvtpk(a[c1 + 6], a[c1 + 7]);
            asm("v_permlane32_swap_b32 %0, %1" : "+v"(W0), "+v"(W2));
            asm("v_permlane32_swap_b32 %0, %1" : "+v"(W1), "+v"(W3));
            uint4v pw;
            pw.x = W0; pw.y = W1; pw.z = W2; pw.w = W3;
            pf[kc] = *reinterpret_cast<short8*>(&pw);
        }

        // ---- V prefetch (2 pairs), then sums (hide under PV), then PV ----
        short8 vf[3][2];
        {
            int co0 = ((0 + hi) ^ (q & 7)) * 16;     // kc=0 for i=0,1
            vf[0][0] = *(const short8*)(Vh + (0 * 32 + q) * 128 + co0);
            vf[0][1] = *(const short8*)(Vh + (1 * 32 + q) * 128 + co0);
            vf[1][0] = *(const short8*)(Vh + (2 * 32 + q) * 128 + co0);
            vf[1][1] = *(const short8*)(Vh + (3 * 32 + q) * 128 + co0);
        }
        // lane-partial sum tree (cross-half shfl deferred to after the loop)
        float s0 = ((acc0[0]+acc0[1])+(acc0[2]+acc0[3]))
                 + ((acc0[4]+acc0[5])+(acc0[6]+acc0[7]));
        float s1 = ((acc0[8]+acc0[9])+(acc0[10]+acc0[11]))
                 + ((acc0[12]+acc0[13])+(acc0[14]+acc0[15]));
        float s2 = ((acc1[0]+acc1[1])+(acc1[2]+acc1[3]))
                 + ((acc1[4]+acc1[5])+(acc1[6]+acc1[7]));
        float s3 = ((acc1[8]+acc1[9])+(acc1[10]+acc1[11]))
                 + ((acc1[12]+acc1[13])+(acc1[14]+acc1[15]));
        lsum += (s0 + s1) + (s2 + s3);

        // ---- O^T += V^T P^T, rotating prefetch (2 read-pairs in flight) ----
        // Linear order i = kc*4+dt: vf for step s+2 issued at step s.
        __builtin_amdgcn_s_setprio(1);
        #pragma unroll
        for (int s = 0; s < 8; ++s) {
            if (s < 6) {
                int i0 = 2 * s + 4, i1 = 2 * s + 5;
                int coA = (((i0 >> 2) * 2 + hi) ^ (q & 7)) * 16;
                int coB = (((i1 >> 2) * 2 + hi) ^ (q & 7)) * 16;
                vf[(s + 2) % 3][0] = *(const short8*)(Vh + ((i0 & 3) * 32 + q) * 128 + coA);
                vf[(s + 2) % 3][1] = *(const short8*)(Vh + ((i1 & 3) * 32 + q) * 128 + coB);
            }
            o[(2 * s) & 3] = __builtin_amdgcn_mfma_f32_32x32x16_bf16(
                vf[s % 3][0], pf[(2 * s) >> 2], o[(2 * s) & 3], 0, 0, 0);
            o[(2 * s + 1) & 3] = __builtin_amdgcn_mfma_f32_32x32x16_bf16(
                vf[s % 3][1], pf[(2 * s + 1) >> 2], o[(2 * s + 1) & 3], 0, 0, 0);
        }
        __builtin_amdgcn_s_setprio(0);

        __syncthreads();     // reads of buf[cur] done + DMA into buf[cur^1] drained
        cur ^= 1;
    }

    // Complete the cross-half lsum reduction once (exact: halves share m).
    lsum += __shfl_xor(lsum, 32);

    // ---- merge halves through LDS, residual-fused transposed writeout ----
    if (half == 1) {
        float* obuf = (float*)(smem + ww * 16384);
        #pragma unroll
        for (int dt = 0; dt < 4; ++dt)
            #pragma unroll
            for (int r = 0; r < 16; ++r) {
                int dl = dt * 32 + (r & 3) + 8 * (r >> 2) + 4 * hi;
                obuf[dl * 32 + q] = o[dt][r];
            }
        if (hi == 0) {
            float* ml = (float*)(smem + 65536 + ww * 256);
            ml[q * 2]     = m;
            ml[q * 2 + 1] = lsum;
        }
    }
    __syncthreads();
    if (half == 0) {
        const float* obuf = (const float*)(smem + ww * 16384);
        const float* ml   = (const float*)(smem + 65536 + ww * 256);
        float m2 = ml[q * 2], l2 = ml[q * 2 + 1];
        float M  = fmaxf(m, m2);
        float c1 = EXP2F(m - M), c2 = EXP2F(m2 - M);
        float inv = 1.0f / (lsum * c1 + l2 * c2);
        const float* xb = x   + (size_t)b * D_ * S_;
        float*       ob = out + (size_t)b * D_ * S_;
        int s = q0 + ww * 32 + q;
        #pragma unroll
        for (int dt = 0; dt < 4; ++dt)
            #pragma unroll
            for (int r = 0; r < 16; ++r) {
                int dl = dt * 32 + (r & 3) + 8 * (r >> 2) + 4 * hi;
                float val = (o[dt][r] * c1 + obuf[dl * 32 + q] * c2) * inv;
                size_t g = (size_t)dl * S_ + s;
                ob[g] = xb[g] + val;
            }
    }
}

extern "C" void kernel_launch(void* const* d_in, const int* in_sizes, int n_in,
                              void* d_out, int out_size, void* d_ws, size_t ws_size,
                              hipStream_t stream) {
    const float* x  = (const float*)d_in[0];
    const float* Wq = (const float*)d_in[1];
    const float* bq = (const float*)d_in[2];
    const float* Wk = (const float*)d_in[3];
    const float* bk = (const float*)d_in[4];
    const float* Wv = (const float*)d_in[5];
    const float* bv = (const float*)d_in[6];
    float* out = (float*)d_out;

    size_t n = (size_t)B_ * S_ * D_;
    short* Qw = (short*)d_ws;
    short* Kw = Qw + n;
    short* Vw = Kw + n;
    short* Wf = (short*)d_out;   // scratch at head of d_out; fully overwritten

    wpack_kernel<<<24, 256, 0, stream>>>(Wq, Wk, Wv, Wf);

    dim3 grid(S_ / 64, B_);
    qkv_kernel<<<grid, 256, 0, stream>>>(x, Wf, bq, bk, bv, Qw, Kw, Vw);

    int smemB = 131072;
    (void)hipFuncSetAttribute((const void*)attn_kernel,
                              hipFuncAttributeMaxDynamicSharedMemorySize, smemB);
    attn_kernel<<<256, 512, smemB, stream>>>(Qw, Kw, Vw, x, out);
}